// Round 4
// baseline (894.041 us; speedup 1.0000x reference)
//
#include <hip/hip_runtime.h>
#include <stdint.h>

#define B_DIM 8
#define L_DIM 4096
#define D_DIM 1024
#define S_DIM 256
#define N_DIM 3

#define NT 256

// bf16-split MFMA scoring:
//   score(t,s,i) = dot(x[t], mem[s,i]) + pb[s,i]
//   x = hi + lo (bf16 RNE each), mem = mhi + mlo;
//   score ~= x_hi*m_hi + x_lo*m_hi + x_hi*m_lo  (residual x_lo*m_lo ~ 1e-4 sigma)
// Items whose top1-top2 gap <= EPS_GAP (~600 sigma) are re-resolved in exact fp32
// with the baseline's proven blocked-sum ordering.
#define EPS_GAP 0.0625f
#define WCAP 65536

typedef __attribute__((ext_vector_type(8))) short bf16x8;  // 8 bf16 (4 VGPRs)
typedef __attribute__((ext_vector_type(4))) float f32x4;

__device__ __forceinline__ float4 ld4(const float* p) {
    return *reinterpret_cast<const float4*>(p);
}

// async global->LDS, 16B per lane. LDS dest must be linear (base + lane*16).
__device__ __forceinline__ void gl_lds16(const void* g, void* l) {
    __builtin_amdgcn_global_load_lds(
        (const __attribute__((address_space(1))) void*)(uintptr_t)g,
        (__attribute__((address_space(3))) void*)(uint32_t)(uintptr_t)l,
        16, 0, 0);
}

__device__ __forceinline__ unsigned short f2bf(float f) {
    const uint32_t u = __float_as_uint(f);
    return (unsigned short)((u + 0x7fffu + ((u >> 16) & 1u)) >> 16);  // RNE
}
__device__ __forceinline__ float bf2f(unsigned short h) {
    return __uint_as_float((uint32_t)h << 16);
}

// ---------------------------------------------------------------------------
// split fp32 -> (hi, lo) bf16 arrays (mem only: 3 MB); also zeroes counter.
__global__ __launch_bounds__(NT)
void split_bf16_kernel(const float* __restrict__ src,
                       unsigned short* __restrict__ hi,
                       unsigned short* __restrict__ lo,
                       int* __restrict__ counter, int n4)
{
    if (blockIdx.x == 0 && threadIdx.x == 0) *counter = 0;
    const int stride = gridDim.x * NT;
    for (int idx = blockIdx.x * NT + threadIdx.x; idx < n4; idx += stride) {
        const float4 v = ld4(src + (size_t)idx * 4);
        const float vv[4] = {v.x, v.y, v.z, v.w};
        uint32_t hw[2], lw[2];
        #pragma unroll
        for (int c = 0; c < 2; ++c) {
            const unsigned short h0 = f2bf(vv[2 * c]);
            const unsigned short h1 = f2bf(vv[2 * c + 1]);
            const float r0 = vv[2 * c]     - bf2f(h0);
            const float r1 = vv[2 * c + 1] - bf2f(h1);
            hw[c] = (uint32_t)h0 | ((uint32_t)h1 << 16);
            lw[c] = (uint32_t)f2bf(r0) | ((uint32_t)f2bf(r1) << 16);
        }
        uint2 hv; hv.x = hw[0]; hv.y = hw[1];
        uint2 lv; lv.x = lw[0]; lv.y = lw[1];
        *reinterpret_cast<uint2*>(hi + (size_t)idx * 4) = hv;
        *reinterpret_cast<uint2*>(lo + (size_t)idx * 4) = lv;
    }
}

// ---------------------------------------------------------------------------
// MFMA scoring + top2 + argmax.  Block = 128 rows x 256 cols, one i.
// 4 waves: wave w -> row-group wr=w>>1 (64 rows), col-group wc=w&1 (128 cols);
// per wave m=4 x n=8 tiles of 16x16x32 MFMA, 3 split-segments fused per k0.
// x is converted fp32->(hi,lo) bf16 during A staging (no global split arrays).
// LDS tiles [row][k] bf16, 16B-block index XOR-swizzled with (row>>1)&3;
// B stages via global_load_lds with pre-swizzled GLOBAL source (linear dest).
// LDS = 48 KB exactly (cand overlays the A tiles) -> 3 blocks/CU; grid = 768
// blocks = 256 CUs x 3: one perfectly balanced dispatch round, 12 waves/CU
// to hide the per-k0 barrier vmcnt drain.
__global__ __launch_bounds__(NT, 3)
void score_mfma_kernel(const float* __restrict__ x,
                       const unsigned short* __restrict__ mhi,
                       const unsigned short* __restrict__ mlo,
                       const float* __restrict__ pb,
                       int* __restrict__ best,
                       int* __restrict__ counter,
                       int* __restrict__ worklist)
{
    __shared__ __align__(16) unsigned short Ahi[128 * 32];   // 8 KB
    __shared__ __align__(16) unsigned short Alo[128 * 32];   // 8 KB
    __shared__ __align__(16) unsigned short Bhi[S_DIM * 32]; // 16 KB
    __shared__ __align__(16) unsigned short Blo[S_DIM * 32]; // 16 KB
    // cand (4 KB) overlays Ahi: only touched after the k-loop + barrier.
    float (*cand)[128][4] = (float (*)[128][4])Ahi;

    const int tid  = threadIdx.x;
    const int lane = tid & 63;
    const int w    = tid >> 6;
    const int wr   = w >> 1;     // row-group 0..1
    const int wc   = w & 1;      // col-group 0..1
    const int l15  = lane & 15;
    const int l4   = lane >> 4;
    const int t0   = blockIdx.x * 128;
    const int i    = blockIdx.y;

    // B staging source offsets: LDS slot f holds global k-block (f&3)^sw(s)
    size_t b_off[4];
    #pragma unroll
    for (int p = 0; p < 4; ++p) {
        const int f = tid + p * NT;
        const int s = f >> 2;
        const int bb = (f & 3) ^ ((s >> 1) & 3);
        b_off[p] = (size_t)(s * N_DIM + i) * D_DIM + (size_t)(bb * 8);
    }

    // fragment read offsets (ushort units): lane holds row|col = l15, k-blk = l4
    int a_rd[4], b_rd[8], scol[8];
    #pragma unroll
    for (int m = 0; m < 4; ++m) {
        const int r = wr * 64 + m * 16 + l15;
        a_rd[m] = r * 32 + (l4 ^ ((r >> 1) & 3)) * 8;
    }
    #pragma unroll
    for (int n = 0; n < 8; ++n) {
        const int s = wc * 128 + n * 16 + l15;
        scol[n] = s;
        b_rd[n] = s * 32 + (l4 ^ ((s >> 1) & 3)) * 8;
    }

    float pbv[8];
    #pragma unroll
    for (int n = 0; n < 8; ++n) pbv[n] = pb[scol[n] * N_DIM + i];

    f32x4 acc[4][8];
    const f32x4 zero = {0.f, 0.f, 0.f, 0.f};
    #pragma unroll
    for (int m = 0; m < 4; ++m)
        #pragma unroll
        for (int n = 0; n < 8; ++n) acc[m][n] = zero;

    for (int k0 = 0; k0 < D_DIM; k0 += 32) {
        __syncthreads();  // previous tile fully consumed

        // issue async B loads first (latency hides under A conversion)
        #pragma unroll
        for (int p = 0; p < 4; ++p) {
            gl_lds16(mhi + b_off[p] + k0, &Bhi[(tid + p * NT) * 8]);
            gl_lds16(mlo + b_off[p] + k0, &Blo[(tid + p * NT) * 8]);
        }
        // A tile: load fp32, split to (hi,lo) bf16, swizzled ds_write_b128
        #pragma unroll
        for (int p = 0; p < 2; ++p) {
            const int f  = tid + p * NT;
            const int r  = f >> 2;
            const int jb = f & 3;
            const int sb = jb ^ ((r >> 1) & 3);
            const float* px = x + (size_t)(t0 + r) * D_DIM + k0 + jb * 8;
            const float4 v0 = ld4(px);
            const float4 v1 = ld4(px + 4);
            const float vv[8] = {v0.x, v0.y, v0.z, v0.w, v1.x, v1.y, v1.z, v1.w};
            uint32_t hws[4], lws[4];
            #pragma unroll
            for (int c = 0; c < 4; ++c) {
                const unsigned short ha = f2bf(vv[2 * c]);
                const unsigned short hb = f2bf(vv[2 * c + 1]);
                const float ra = vv[2 * c]     - bf2f(ha);
                const float rb = vv[2 * c + 1] - bf2f(hb);
                hws[c] = (uint32_t)ha | ((uint32_t)hb << 16);
                lws[c] = (uint32_t)f2bf(ra) | ((uint32_t)f2bf(rb) << 16);
            }
            uint4 hw; hw.x = hws[0]; hw.y = hws[1]; hw.z = hws[2]; hw.w = hws[3];
            uint4 lw; lw.x = lws[0]; lw.y = lws[1]; lw.z = lws[2]; lw.w = lws[3];
            *reinterpret_cast<uint4*>(&Ahi[r * 32 + sb * 8]) = hw;
            *reinterpret_cast<uint4*>(&Alo[r * 32 + sb * 8]) = lw;
        }
        __syncthreads();  // compiler drains vmcnt+lgkmcnt before barrier

        bf16x8 ah[4], al[4];
        #pragma unroll
        for (int m = 0; m < 4; ++m) {
            ah[m] = *reinterpret_cast<const bf16x8*>(&Ahi[a_rd[m]]);
            al[m] = *reinterpret_cast<const bf16x8*>(&Alo[a_rd[m]]);
        }
        #pragma unroll
        for (int n = 0; n < 8; ++n) {
            const bf16x8 bh = *reinterpret_cast<const bf16x8*>(&Bhi[b_rd[n]]);
            const bf16x8 bl = *reinterpret_cast<const bf16x8*>(&Blo[b_rd[n]]);
            #pragma unroll
            for (int m = 0; m < 4; ++m)
                acc[m][n] = __builtin_amdgcn_mfma_f32_16x16x32_bf16(ah[m], bh, acc[m][n], 0, 0, 0);
            #pragma unroll
            for (int m = 0; m < 4; ++m)
                acc[m][n] = __builtin_amdgcn_mfma_f32_16x16x32_bf16(al[m], bh, acc[m][n], 0, 0, 0);
            #pragma unroll
            for (int m = 0; m < 4; ++m)
                acc[m][n] = __builtin_amdgcn_mfma_f32_16x16x32_bf16(ah[m], bl, acc[m][n], 0, 0, 0);
        }
    }

    __syncthreads();  // all waves done reading A/B before cand overlays Ahi

    // ---- epilogue: + pos_bias, per-row top2 over this wave's 128 cols.
    // C/D layout (m89-verified): col = lane&15, row = (lane>>4)*4 + reg_idx.
    #pragma unroll
    for (int m = 0; m < 4; ++m) {
        #pragma unroll
        for (int j = 0; j < 4; ++j) {
            float v1 = -3.0e38f, v2 = -3.0e38f;
            int s1 = 0;
            #pragma unroll
            for (int n = 0; n < 8; ++n) {  // s ascending in n -> first-max kept
                const float v = acc[m][n][j] + pbv[n];
                if (v > v1) { v2 = v1; v1 = v; s1 = scol[n]; }
                else if (v > v2) { v2 = v; }
            }
            #pragma unroll
            for (int off = 1; off < 16; off <<= 1) {  // 16 column lanes
                const float ov1 = __shfl_xor(v1, off);
                const float ov2 = __shfl_xor(v2, off);
                const int   os1 = __shfl_xor(s1, off);
                if (ov1 > v1 || (ov1 == v1 && os1 < s1)) {
                    v2 = fmaxf(v1, ov2);
                    v1 = ov1; s1 = os1;
                } else {
                    v2 = fmaxf(v2, ov1);
                }
            }
            if (l15 == 0) {
                const int row = wr * 64 + m * 16 + l4 * 4 + j;
                cand[wc][row][0] = v1;
                cand[wc][row][1] = __int_as_float(s1);
                cand[wc][row][2] = v2;
            }
        }
    }
    __syncthreads();
    if (tid < 128) {
        const int row = tid;
        float v1  = cand[0][row][0];
        int   s1  = __float_as_int(cand[0][row][1]);
        float v2  = cand[0][row][2];
        const float a1  = cand[1][row][0];   // group 1: all s >= 128 > s1
        const int   as1 = __float_as_int(cand[1][row][1]);
        const float a2  = cand[1][row][2];
        if (a1 > v1) { v2 = fmaxf(v1, a2); v1 = a1; s1 = as1; }
        else         { v2 = fmaxf(v2, a1); }
        const int item = (t0 + row) * N_DIM + i;
        best[item] = s1;
        if (v1 - v2 <= EPS_GAP) {  // ambiguous under split error -> exact pass
            const int idx = atomicAdd(counter, 1);
            if (idx < WCAP) worklist[idx] = item;
        }
    }
}

// ---------------------------------------------------------------------------
// exact fp32 re-resolution of flagged (t,i) items (expected ~1e2-1e3);
// identical blocked-sum ordering to the proven fp32 baseline.
__global__ __launch_bounds__(NT)
void exact_fix_kernel(const float* __restrict__ x,
                      const float* __restrict__ mem,
                      const float* __restrict__ pb,
                      const int* __restrict__ counter,
                      const int* __restrict__ worklist,
                      int* __restrict__ best)
{
    __shared__ float xl[D_DIM];
    __shared__ float sv[NT];
    __shared__ int   si[NT];
    int cnt = *counter;
    if (cnt > WCAP) cnt = WCAP;
    for (int w = blockIdx.x; w < cnt; w += gridDim.x) {
        const int item = worklist[w];
        const int t  = item / N_DIM;
        const int ii = item - t * N_DIM;
        __syncthreads();
        #pragma unroll
        for (int p = 0; p < D_DIM / NT; ++p)
            xl[threadIdx.x + p * NT] = x[(size_t)t * D_DIM + threadIdx.x + p * NT];
        __syncthreads();
        const int s = threadIdx.x;
        const float* mr = mem + ((size_t)s * N_DIM + ii) * D_DIM;
        float acc = 0.f;
        for (int kb = 0; kb < D_DIM; kb += 32) {  // blocked sum, err ~1e-5
            float part = 0.f;
            #pragma unroll
            for (int k = 0; k < 32; ++k) part += xl[kb + k] * mr[kb + k];
            acc += part;
        }
        sv[s] = acc + pb[s * N_DIM + ii];
        si[s] = s;
        __syncthreads();
        for (int off = NT / 2; off >= 1; off >>= 1) {  // first-max semantics
            if (threadIdx.x < off) {
                const float b2 = sv[threadIdx.x + off];
                const int  bi2 = si[threadIdx.x + off];
                if (b2 > sv[threadIdx.x] ||
                    (b2 == sv[threadIdx.x] && bi2 < si[threadIdx.x])) {
                    sv[threadIdx.x] = b2; si[threadIdx.x] = bi2;
                }
            }
            __syncthreads();
        }
        if (threadIdx.x == 0) best[item] = si[0];
    }
}

// ---------------------------------------------------------------------------
// out[b,l,:] = sum_i mem[best_i, i, :]
__global__ __launch_bounds__(NT)
void gather_sum_kernel(const float* __restrict__ mem,
                       const float* __restrict__ pb,
                       const int* __restrict__ best,
                       float* __restrict__ out)
{
    const int bl = blockIdx.x;
    const int l = bl & (L_DIM - 1);
    __shared__ int sbi[N_DIM];
    if (threadIdx.x < N_DIM) {
        const int i = threadIdx.x;
        const int t = l + i - (N_DIM - 1);
        int bi;
        if (t >= 0) {
            bi = best[(bl + i - (N_DIM - 1)) * N_DIM + i];
        } else {
            float bv = pb[i];  // zero ngram row: argmax over pos_bias (l < 2)
            bi = 0;
            for (int s = 1; s < S_DIM; ++s) {
                const float v = pb[s * N_DIM + i];
                if (v > bv) { bv = v; bi = s; }
            }
        }
        sbi[i] = bi;
    }
    __syncthreads();
    const int d = threadIdx.x;
    const float4 v0 = ld4(mem + (sbi[0] * N_DIM + 0) * D_DIM + d * 4);
    const float4 v1 = ld4(mem + (sbi[1] * N_DIM + 1) * D_DIM + d * 4);
    const float4 v2 = ld4(mem + (sbi[2] * N_DIM + 2) * D_DIM + d * 4);
    float4 r;
    r.x = (v0.x + v1.x) + v2.x;
    r.y = (v0.y + v1.y) + v2.y;
    r.z = (v0.z + v1.z) + v2.z;
    r.w = (v0.w + v1.w) + v2.w;
    *reinterpret_cast<float4*>(out + bl * D_DIM + d * 4) = r;
}

// ---------------------------------------------------------------------------
extern "C" void kernel_launch(void* const* d_in, const int* in_sizes, int n_in,
                              void* d_out, int out_size, void* d_ws, size_t ws_size,
                              hipStream_t stream)
{
    const float* x   = (const float*)d_in[0];   // (B, L, D) fp32
    const float* mem = (const float*)d_in[1];   // (S, N, D) fp32
    const float* pb  = (const float*)d_in[2];   // (S, N) fp32
    float* out = (float*)d_out;
    int* best = (int*)d_ws;  // 384 KB — exactly what the proven baseline used

    const int n_rows = B_DIM * L_DIM;           // 32768

    // scratch inside d_out (128 MiB by problem shape; every byte dead before
    // gather_sum rewrites it):  [0,3MiB): mhi,mlo   [4MiB): counter, worklist
    char* ob = (char*)d_out;
    unsigned short* mhi = (unsigned short*)ob;
    unsigned short* mlo = mhi + (size_t)S_DIM * N_DIM * D_DIM;
    int* counter  = (int*)(ob + ((size_t)4 << 20));
    int* worklist = (int*)(ob + ((size_t)4 << 20) + 256);

    split_bf16_kernel<<<192, NT, 0, stream>>>(mem, mhi, mlo, counter,
                                              S_DIM * N_DIM * D_DIM / 4);
    score_mfma_kernel<<<dim3(n_rows / 128, N_DIM), NT, 0, stream>>>(
        x, mhi, mlo, pb, best, counter, worklist);
    exact_fix_kernel<<<512, NT, 0, stream>>>(x, mem, pb, counter, worklist, best);
    gather_sum_kernel<<<n_rows, NT, 0, stream>>>(mem, pb, best, out);
}

// Round 5
// 475.158 us; speedup vs baseline: 1.8816x; 1.8816x over previous
//
#include <hip/hip_runtime.h>
#include <stdint.h>

#define B_DIM 8
#define L_DIM 4096
#define D_DIM 1024
#define S_DIM 256
#define N_DIM 3

#define NT 256

// bf16-split MFMA scoring:
//   score(t,s,i) = dot(x[t], mem[s,i]) + pb[s,i]
//   x = hi + lo (bf16 RNE each), mem = mhi + mlo;
//   score ~= x_hi*m_hi + x_lo*m_hi + x_hi*m_lo  (residual x_lo*m_lo ~ 1e-4 sigma)
// Items whose top1-top2 gap <= EPS_GAP (~600 sigma) are re-resolved in exact fp32
// with the baseline's proven blocked-sum ordering.
#define EPS_GAP 0.0625f
#define WCAP 65536

typedef __attribute__((ext_vector_type(8))) short bf16x8;  // 8 bf16 (4 VGPRs)
typedef __attribute__((ext_vector_type(4))) float f32x4;

__device__ __forceinline__ float4 ld4(const float* p) {
    return *reinterpret_cast<const float4*>(p);
}

// async global->LDS, 16B per lane. LDS dest must be linear (base + lane*16).
__device__ __forceinline__ void gl_lds16(const void* g, void* l) {
    __builtin_amdgcn_global_load_lds(
        (const __attribute__((address_space(1))) void*)(uintptr_t)g,
        (__attribute__((address_space(3))) void*)(uint32_t)(uintptr_t)l,
        16, 0, 0);
}

__device__ __forceinline__ unsigned short f2bf(float f) {
    const uint32_t u = __float_as_uint(f);
    return (unsigned short)((u + 0x7fffu + ((u >> 16) & 1u)) >> 16);  // RNE
}
__device__ __forceinline__ float bf2f(unsigned short h) {
    return __uint_as_float((uint32_t)h << 16);
}

// ---------------------------------------------------------------------------
// split fp32 -> (hi, lo) bf16 arrays (mem only: 3 MB); also zeroes counter.
__global__ __launch_bounds__(NT)
void split_bf16_kernel(const float* __restrict__ src,
                       unsigned short* __restrict__ hi,
                       unsigned short* __restrict__ lo,
                       int* __restrict__ counter, int n4)
{
    if (blockIdx.x == 0 && threadIdx.x == 0) *counter = 0;
    const int stride = gridDim.x * NT;
    for (int idx = blockIdx.x * NT + threadIdx.x; idx < n4; idx += stride) {
        const float4 v = ld4(src + (size_t)idx * 4);
        const float vv[4] = {v.x, v.y, v.z, v.w};
        uint32_t hw[2], lw[2];
        #pragma unroll
        for (int c = 0; c < 2; ++c) {
            const unsigned short h0 = f2bf(vv[2 * c]);
            const unsigned short h1 = f2bf(vv[2 * c + 1]);
            const float r0 = vv[2 * c]     - bf2f(h0);
            const float r1 = vv[2 * c + 1] - bf2f(h1);
            hw[c] = (uint32_t)h0 | ((uint32_t)h1 << 16);
            lw[c] = (uint32_t)f2bf(r0) | ((uint32_t)f2bf(r1) << 16);
        }
        uint2 hv; hv.x = hw[0]; hv.y = hw[1];
        uint2 lv; lv.x = lw[0]; lv.y = lw[1];
        *reinterpret_cast<uint2*>(hi + (size_t)idx * 4) = hv;
        *reinterpret_cast<uint2*>(lo + (size_t)idx * 4) = lv;
    }
}

// ---------------------------------------------------------------------------
// MFMA scoring + top2 + argmax.  Block = 64 rows x 256 cols, one i.
// 4 waves, pure COLUMN split: wave w covers cols [w*64, w*64+64); wave tile
// 64x64 = m4 x n4 of 16x16x32 MFMA, acc = 64 regs/thread (fits 4 waves/SIMD
// with NO spills -- round-4's forced (NT,3) spilled the 128-reg acc to
// scratch: WRITE_SIZE 0.8MB -> 1.3GB. Occupancy comes from tile size now.)
// 3 split-segments fused per k0, BK=32.
// x is converted fp32->(hi,lo) bf16 during A staging (no global split arrays).
// LDS tiles [row][k] bf16, 16B-block index XOR-swizzled with (row>>1)&3;
// B stages via global_load_lds with pre-swizzled GLOBAL source (linear dest).
// LDS = 40 KB -> 4 blocks/CU (160 KB), 16 waves/CU to hide the barrier drain.
__global__ __launch_bounds__(NT, 2)
void score_mfma_kernel(const float* __restrict__ x,
                       const unsigned short* __restrict__ mhi,
                       const unsigned short* __restrict__ mlo,
                       const float* __restrict__ pb,
                       int* __restrict__ best,
                       int* __restrict__ counter,
                       int* __restrict__ worklist)
{
    __shared__ __align__(16) unsigned short Ahi[64 * 32];    // 4 KB
    __shared__ __align__(16) unsigned short Alo[64 * 32];    // 4 KB
    __shared__ __align__(16) unsigned short Bhi[S_DIM * 32]; // 16 KB
    __shared__ __align__(16) unsigned short Blo[S_DIM * 32]; // 16 KB
    // cand (4 KB) overlays Ahi: only touched after the k-loop + barrier.
    float (*cand)[64][4] = (float (*)[64][4])Ahi;

    const int tid  = threadIdx.x;
    const int lane = tid & 63;
    const int wc   = tid >> 6;   // col-group 0..3 (cols wc*64 .. wc*64+63)
    const int l15  = lane & 15;
    const int l4   = lane >> 4;
    const int t0   = blockIdx.x * 64;
    const int i    = blockIdx.y;

    // B staging source offsets: LDS slot f holds global k-block (f&3)^sw(s)
    size_t b_off[4];
    #pragma unroll
    for (int p = 0; p < 4; ++p) {
        const int f = tid + p * NT;
        const int s = f >> 2;
        const int bb = (f & 3) ^ ((s >> 1) & 3);
        b_off[p] = (size_t)(s * N_DIM + i) * D_DIM + (size_t)(bb * 8);
    }
    // A staging: 64 rows x 32 k = 256 slots = exactly one pass
    const int ar  = tid >> 2;          // row 0..63
    const int ajb = tid & 3;           // global k-block
    const int asb = ajb ^ ((ar >> 1) & 3);  // swizzled LDS k-block
    const float* axp = x + (size_t)(t0 + ar) * D_DIM + ajb * 8;

    // fragment read offsets (ushort units): lane holds row|col = l15, k-blk = l4
    int a_rd[4], b_rd[4], scol[4];
    #pragma unroll
    for (int m = 0; m < 4; ++m) {
        const int r = m * 16 + l15;
        a_rd[m] = r * 32 + (l4 ^ ((r >> 1) & 3)) * 8;
    }
    #pragma unroll
    for (int n = 0; n < 4; ++n) {
        const int s = wc * 64 + n * 16 + l15;
        scol[n] = s;
        b_rd[n] = s * 32 + (l4 ^ ((s >> 1) & 3)) * 8;
    }

    float pbv[4];
    #pragma unroll
    for (int n = 0; n < 4; ++n) pbv[n] = pb[scol[n] * N_DIM + i];

    f32x4 acc[4][4];
    const f32x4 zero = {0.f, 0.f, 0.f, 0.f};
    #pragma unroll
    for (int m = 0; m < 4; ++m)
        #pragma unroll
        for (int n = 0; n < 4; ++n) acc[m][n] = zero;

    for (int k0 = 0; k0 < D_DIM; k0 += 32) {
        __syncthreads();  // previous tile fully consumed

        // issue async B loads first (latency hides under A conversion)
        #pragma unroll
        for (int p = 0; p < 4; ++p) {
            gl_lds16(mhi + b_off[p] + k0, &Bhi[(tid + p * NT) * 8]);
            gl_lds16(mlo + b_off[p] + k0, &Blo[(tid + p * NT) * 8]);
        }
        // A tile: load fp32, split to (hi,lo) bf16, swizzled ds_write_b128
        {
            const float4 v0 = ld4(axp + k0);
            const float4 v1 = ld4(axp + k0 + 4);
            const float vv[8] = {v0.x, v0.y, v0.z, v0.w, v1.x, v1.y, v1.z, v1.w};
            uint32_t hws[4], lws[4];
            #pragma unroll
            for (int c = 0; c < 4; ++c) {
                const unsigned short ha = f2bf(vv[2 * c]);
                const unsigned short hb = f2bf(vv[2 * c + 1]);
                const float ra = vv[2 * c]     - bf2f(ha);
                const float rb = vv[2 * c + 1] - bf2f(hb);
                hws[c] = (uint32_t)ha | ((uint32_t)hb << 16);
                lws[c] = (uint32_t)f2bf(ra) | ((uint32_t)f2bf(rb) << 16);
            }
            uint4 hw; hw.x = hws[0]; hw.y = hws[1]; hw.z = hws[2]; hw.w = hws[3];
            uint4 lw; lw.x = lws[0]; lw.y = lws[1]; lw.z = lws[2]; lw.w = lws[3];
            *reinterpret_cast<uint4*>(&Ahi[ar * 32 + asb * 8]) = hw;
            *reinterpret_cast<uint4*>(&Alo[ar * 32 + asb * 8]) = lw;
        }
        __syncthreads();  // compiler drains vmcnt+lgkmcnt before barrier

        bf16x8 ah[4], al[4];
        #pragma unroll
        for (int m = 0; m < 4; ++m) {
            ah[m] = *reinterpret_cast<const bf16x8*>(&Ahi[a_rd[m]]);
            al[m] = *reinterpret_cast<const bf16x8*>(&Alo[a_rd[m]]);
        }
        #pragma unroll
        for (int n = 0; n < 4; ++n) {
            const bf16x8 bh = *reinterpret_cast<const bf16x8*>(&Bhi[b_rd[n]]);
            const bf16x8 bl = *reinterpret_cast<const bf16x8*>(&Blo[b_rd[n]]);
            #pragma unroll
            for (int m = 0; m < 4; ++m)
                acc[m][n] = __builtin_amdgcn_mfma_f32_16x16x32_bf16(ah[m], bh, acc[m][n], 0, 0, 0);
            #pragma unroll
            for (int m = 0; m < 4; ++m)
                acc[m][n] = __builtin_amdgcn_mfma_f32_16x16x32_bf16(al[m], bh, acc[m][n], 0, 0, 0);
            #pragma unroll
            for (int m = 0; m < 4; ++m)
                acc[m][n] = __builtin_amdgcn_mfma_f32_16x16x32_bf16(ah[m], bl, acc[m][n], 0, 0, 0);
        }
    }

    __syncthreads();  // all waves done reading A/B before cand overlays Ahi

    // ---- epilogue: + pos_bias, per-row top2 over this wave's 64 cols.
    // C/D layout (m89-verified): col = lane&15, row = (lane>>4)*4 + reg_idx.
    #pragma unroll
    for (int m = 0; m < 4; ++m) {
        #pragma unroll
        for (int j = 0; j < 4; ++j) {
            float v1 = -3.0e38f, v2 = -3.0e38f;
            int s1 = 0;
            #pragma unroll
            for (int n = 0; n < 4; ++n) {  // s ascending in n -> first-max kept
                const float v = acc[m][n][j] + pbv[n];
                if (v > v1) { v2 = v1; v1 = v; s1 = scol[n]; }
                else if (v > v2) { v2 = v; }
            }
            #pragma unroll
            for (int off = 1; off < 16; off <<= 1) {  // 16 column lanes
                const float ov1 = __shfl_xor(v1, off);
                const float ov2 = __shfl_xor(v2, off);
                const int   os1 = __shfl_xor(s1, off);
                if (ov1 > v1 || (ov1 == v1 && os1 < s1)) {
                    v2 = fmaxf(v1, ov2);
                    v1 = ov1; s1 = os1;
                } else {
                    v2 = fmaxf(v2, ov1);
                }
            }
            if (l15 == 0) {
                const int row = m * 16 + l4 * 4 + j;
                cand[wc][row][0] = v1;
                cand[wc][row][1] = __int_as_float(s1);
                cand[wc][row][2] = v2;
            }
        }
    }
    __syncthreads();
    if (tid < 64) {
        const int row = tid;
        float v1 = cand[0][row][0];
        int   s1 = __float_as_int(cand[0][row][1]);
        float v2 = cand[0][row][2];
        #pragma unroll
        for (int g = 1; g < 4; ++g) {   // ascending col-group -> ascending s
            const float a1  = cand[g][row][0];
            const int   as1 = __float_as_int(cand[g][row][1]);
            const float a2  = cand[g][row][2];
            if (a1 > v1) { v2 = fmaxf(v1, a2); v1 = a1; s1 = as1; }
            else         { v2 = fmaxf(v2, a1); }
        }
        const int item = (t0 + row) * N_DIM + i;
        best[item] = s1;
        if (v1 - v2 <= EPS_GAP) {  // ambiguous under split error -> exact pass
            const int idx = atomicAdd(counter, 1);
            if (idx < WCAP) worklist[idx] = item;
        }
    }
}

// ---------------------------------------------------------------------------
// exact fp32 re-resolution of flagged (t,i) items (expected ~1e2-1e3);
// identical blocked-sum ordering to the proven fp32 baseline.
__global__ __launch_bounds__(NT)
void exact_fix_kernel(const float* __restrict__ x,
                      const float* __restrict__ mem,
                      const float* __restrict__ pb,
                      const int* __restrict__ counter,
                      const int* __restrict__ worklist,
                      int* __restrict__ best)
{
    __shared__ float xl[D_DIM];
    __shared__ float sv[NT];
    __shared__ int   si[NT];
    int cnt = *counter;
    if (cnt > WCAP) cnt = WCAP;
    for (int w = blockIdx.x; w < cnt; w += gridDim.x) {
        const int item = worklist[w];
        const int t  = item / N_DIM;
        const int ii = item - t * N_DIM;
        __syncthreads();
        #pragma unroll
        for (int p = 0; p < D_DIM / NT; ++p)
            xl[threadIdx.x + p * NT] = x[(size_t)t * D_DIM + threadIdx.x + p * NT];
        __syncthreads();
        const int s = threadIdx.x;
        const float* mr = mem + ((size_t)s * N_DIM + ii) * D_DIM;
        float acc = 0.f;
        for (int kb = 0; kb < D_DIM; kb += 32) {  // blocked sum, err ~1e-5
            float part = 0.f;
            #pragma unroll
            for (int k = 0; k < 32; ++k) part += xl[kb + k] * mr[kb + k];
            acc += part;
        }
        sv[s] = acc + pb[s * N_DIM + ii];
        si[s] = s;
        __syncthreads();
        for (int off = NT / 2; off >= 1; off >>= 1) {  // first-max semantics
            if (threadIdx.x < off) {
                const float b2 = sv[threadIdx.x + off];
                const int  bi2 = si[threadIdx.x + off];
                if (b2 > sv[threadIdx.x] ||
                    (b2 == sv[threadIdx.x] && bi2 < si[threadIdx.x])) {
                    sv[threadIdx.x] = b2; si[threadIdx.x] = bi2;
                }
            }
            __syncthreads();
        }
        if (threadIdx.x == 0) best[item] = si[0];
    }
}

// ---------------------------------------------------------------------------
// out[b,l,:] = sum_i mem[best_i, i, :]
__global__ __launch_bounds__(NT)
void gather_sum_kernel(const float* __restrict__ mem,
                       const float* __restrict__ pb,
                       const int* __restrict__ best,
                       float* __restrict__ out)
{
    const int bl = blockIdx.x;
    const int l = bl & (L_DIM - 1);
    __shared__ int sbi[N_DIM];
    if (threadIdx.x < N_DIM) {
        const int i = threadIdx.x;
        const int t = l + i - (N_DIM - 1);
        int bi;
        if (t >= 0) {
            bi = best[(bl + i - (N_DIM - 1)) * N_DIM + i];
        } else {
            float bv = pb[i];  // zero ngram row: argmax over pos_bias (l < 2)
            bi = 0;
            for (int s = 1; s < S_DIM; ++s) {
                const float v = pb[s * N_DIM + i];
                if (v > bv) { bv = v; bi = s; }
            }
        }
        sbi[i] = bi;
    }
    __syncthreads();
    const int d = threadIdx.x;
    const float4 v0 = ld4(mem + (sbi[0] * N_DIM + 0) * D_DIM + d * 4);
    const float4 v1 = ld4(mem + (sbi[1] * N_DIM + 1) * D_DIM + d * 4);
    const float4 v2 = ld4(mem + (sbi[2] * N_DIM + 2) * D_DIM + d * 4);
    float4 r;
    r.x = (v0.x + v1.x) + v2.x;
    r.y = (v0.y + v1.y) + v2.y;
    r.z = (v0.z + v1.z) + v2.z;
    r.w = (v0.w + v1.w) + v2.w;
    *reinterpret_cast<float4*>(out + bl * D_DIM + d * 4) = r;
}

// ---------------------------------------------------------------------------
extern "C" void kernel_launch(void* const* d_in, const int* in_sizes, int n_in,
                              void* d_out, int out_size, void* d_ws, size_t ws_size,
                              hipStream_t stream)
{
    const float* x   = (const float*)d_in[0];   // (B, L, D) fp32
    const float* mem = (const float*)d_in[1];   // (S, N, D) fp32
    const float* pb  = (const float*)d_in[2];   // (S, N) fp32
    float* out = (float*)d_out;
    int* best = (int*)d_ws;  // 384 KB — exactly what the proven baseline used

    const int n_rows = B_DIM * L_DIM;           // 32768

    // scratch inside d_out (128 MiB by problem shape; every byte dead before
    // gather_sum rewrites it):  [0,3MiB): mhi,mlo   [4MiB): counter, worklist
    char* ob = (char*)d_out;
    unsigned short* mhi = (unsigned short*)ob;
    unsigned short* mlo = mhi + (size_t)S_DIM * N_DIM * D_DIM;
    int* counter  = (int*)(ob + ((size_t)4 << 20));
    int* worklist = (int*)(ob + ((size_t)4 << 20) + 256);

    split_bf16_kernel<<<192, NT, 0, stream>>>(mem, mhi, mlo, counter,
                                              S_DIM * N_DIM * D_DIM / 4);
    score_mfma_kernel<<<dim3(n_rows / 64, N_DIM), NT, 0, stream>>>(
        x, mhi, mlo, pb, best, counter, worklist);
    exact_fix_kernel<<<512, NT, 0, stream>>>(x, mem, pb, counter, worklist, best);
    gather_sum_kernel<<<n_rows, NT, 0, stream>>>(mem, pb, best, out);
}

// Round 6
// 443.171 us; speedup vs baseline: 2.0174x; 1.0722x over previous
//
#include <hip/hip_runtime.h>
#include <stdint.h>

#define B_DIM 8
#define L_DIM 4096
#define D_DIM 1024
#define S_DIM 256
#define N_DIM 3

#define NT 256
#define GROWS 4   // rows per gather block

// bf16-split MFMA scoring:
//   score(t,s,i) = dot(x[t], mem[s,i]) + pb[s,i]
//   x = hi + lo (bf16 RNE each), mem = mhi + mlo;
//   score ~= x_hi*m_hi + x_lo*m_hi + x_hi*m_lo  (residual x_lo*m_lo ~ 1e-4 sigma)
// Items whose top1-top2 gap <= EPS_GAP (~600 sigma) are re-resolved in exact fp32
// with the baseline's proven blocked-sum ordering (bit-identical FP order; only
// the memory access pattern of that kernel was changed in round 6).
#define EPS_GAP 0.0625f
#define WCAP 65536

typedef __attribute__((ext_vector_type(8))) short bf16x8;  // 8 bf16 (4 VGPRs)
typedef __attribute__((ext_vector_type(4))) float f32x4;

__device__ __forceinline__ float4 ld4(const float* p) {
    return *reinterpret_cast<const float4*>(p);
}

// async global->LDS, 16B per lane. LDS dest must be linear (base + lane*16).
__device__ __forceinline__ void gl_lds16(const void* g, void* l) {
    __builtin_amdgcn_global_load_lds(
        (const __attribute__((address_space(1))) void*)(uintptr_t)g,
        (__attribute__((address_space(3))) void*)(uint32_t)(uintptr_t)l,
        16, 0, 0);
}

__device__ __forceinline__ unsigned short f2bf(float f) {
    const uint32_t u = __float_as_uint(f);
    return (unsigned short)((u + 0x7fffu + ((u >> 16) & 1u)) >> 16);  // RNE
}
__device__ __forceinline__ float bf2f(unsigned short h) {
    return __uint_as_float((uint32_t)h << 16);
}

// ---------------------------------------------------------------------------
// split fp32 -> (hi, lo) bf16 arrays (mem only: 3 MB); also zeroes counter.
__global__ __launch_bounds__(NT)
void split_bf16_kernel(const float* __restrict__ src,
                       unsigned short* __restrict__ hi,
                       unsigned short* __restrict__ lo,
                       int* __restrict__ counter, int n4)
{
    if (blockIdx.x == 0 && threadIdx.x == 0) *counter = 0;
    const int stride = gridDim.x * NT;
    for (int idx = blockIdx.x * NT + threadIdx.x; idx < n4; idx += stride) {
        const float4 v = ld4(src + (size_t)idx * 4);
        const float vv[4] = {v.x, v.y, v.z, v.w};
        uint32_t hw[2], lw[2];
        #pragma unroll
        for (int c = 0; c < 2; ++c) {
            const unsigned short h0 = f2bf(vv[2 * c]);
            const unsigned short h1 = f2bf(vv[2 * c + 1]);
            const float r0 = vv[2 * c]     - bf2f(h0);
            const float r1 = vv[2 * c + 1] - bf2f(h1);
            hw[c] = (uint32_t)h0 | ((uint32_t)h1 << 16);
            lw[c] = (uint32_t)f2bf(r0) | ((uint32_t)f2bf(r1) << 16);
        }
        uint2 hv; hv.x = hw[0]; hv.y = hw[1];
        uint2 lv; lv.x = lw[0]; lv.y = lw[1];
        *reinterpret_cast<uint2*>(hi + (size_t)idx * 4) = hv;
        *reinterpret_cast<uint2*>(lo + (size_t)idx * 4) = lv;
    }
}

// ---------------------------------------------------------------------------
// MFMA scoring + top2 + argmax.  Block = 64 rows x 256 cols, one i.
// (unchanged from round 5: 206 us, MfmaUtil 33%, no spills)
__global__ __launch_bounds__(NT, 2)
void score_mfma_kernel(const float* __restrict__ x,
                       const unsigned short* __restrict__ mhi,
                       const unsigned short* __restrict__ mlo,
                       const float* __restrict__ pb,
                       int* __restrict__ best,
                       int* __restrict__ counter,
                       int* __restrict__ worklist)
{
    __shared__ __align__(16) unsigned short Ahi[64 * 32];    // 4 KB
    __shared__ __align__(16) unsigned short Alo[64 * 32];    // 4 KB
    __shared__ __align__(16) unsigned short Bhi[S_DIM * 32]; // 16 KB
    __shared__ __align__(16) unsigned short Blo[S_DIM * 32]; // 16 KB
    // cand (4 KB) overlays Ahi: only touched after the k-loop + barrier.
    float (*cand)[64][4] = (float (*)[64][4])Ahi;

    const int tid  = threadIdx.x;
    const int lane = tid & 63;
    const int wc   = tid >> 6;   // col-group 0..3 (cols wc*64 .. wc*64+63)
    const int l15  = lane & 15;
    const int l4   = lane >> 4;
    const int t0   = blockIdx.x * 64;
    const int i    = blockIdx.y;

    // B staging source offsets: LDS slot f holds global k-block (f&3)^sw(s)
    size_t b_off[4];
    #pragma unroll
    for (int p = 0; p < 4; ++p) {
        const int f = tid + p * NT;
        const int s = f >> 2;
        const int bb = (f & 3) ^ ((s >> 1) & 3);
        b_off[p] = (size_t)(s * N_DIM + i) * D_DIM + (size_t)(bb * 8);
    }
    // A staging: 64 rows x 32 k = 256 slots = exactly one pass
    const int ar  = tid >> 2;          // row 0..63
    const int ajb = tid & 3;           // global k-block
    const int asb = ajb ^ ((ar >> 1) & 3);  // swizzled LDS k-block
    const float* axp = x + (size_t)(t0 + ar) * D_DIM + ajb * 8;

    // fragment read offsets (ushort units): lane holds row|col = l15, k-blk = l4
    int a_rd[4], b_rd[4], scol[4];
    #pragma unroll
    for (int m = 0; m < 4; ++m) {
        const int r = m * 16 + l15;
        a_rd[m] = r * 32 + (l4 ^ ((r >> 1) & 3)) * 8;
    }
    #pragma unroll
    for (int n = 0; n < 4; ++n) {
        const int s = wc * 64 + n * 16 + l15;
        scol[n] = s;
        b_rd[n] = s * 32 + (l4 ^ ((s >> 1) & 3)) * 8;
    }

    float pbv[4];
    #pragma unroll
    for (int n = 0; n < 4; ++n) pbv[n] = pb[scol[n] * N_DIM + i];

    f32x4 acc[4][4];
    const f32x4 zero = {0.f, 0.f, 0.f, 0.f};
    #pragma unroll
    for (int m = 0; m < 4; ++m)
        #pragma unroll
        for (int n = 0; n < 4; ++n) acc[m][n] = zero;

    for (int k0 = 0; k0 < D_DIM; k0 += 32) {
        __syncthreads();  // previous tile fully consumed

        // issue async B loads first (latency hides under A conversion)
        #pragma unroll
        for (int p = 0; p < 4; ++p) {
            gl_lds16(mhi + b_off[p] + k0, &Bhi[(tid + p * NT) * 8]);
            gl_lds16(mlo + b_off[p] + k0, &Blo[(tid + p * NT) * 8]);
        }
        // A tile: load fp32, split to (hi,lo) bf16, swizzled ds_write_b128
        {
            const float4 v0 = ld4(axp + k0);
            const float4 v1 = ld4(axp + k0 + 4);
            const float vv[8] = {v0.x, v0.y, v0.z, v0.w, v1.x, v1.y, v1.z, v1.w};
            uint32_t hws[4], lws[4];
            #pragma unroll
            for (int c = 0; c < 4; ++c) {
                const unsigned short ha = f2bf(vv[2 * c]);
                const unsigned short hb = f2bf(vv[2 * c + 1]);
                const float ra = vv[2 * c]     - bf2f(ha);
                const float rb = vv[2 * c + 1] - bf2f(hb);
                hws[c] = (uint32_t)ha | ((uint32_t)hb << 16);
                lws[c] = (uint32_t)f2bf(ra) | ((uint32_t)f2bf(rb) << 16);
            }
            uint4 hw; hw.x = hws[0]; hw.y = hws[1]; hw.z = hws[2]; hw.w = hws[3];
            uint4 lw; lw.x = lws[0]; lw.y = lws[1]; lw.z = lws[2]; lw.w = lws[3];
            *reinterpret_cast<uint4*>(&Ahi[ar * 32 + asb * 8]) = hw;
            *reinterpret_cast<uint4*>(&Alo[ar * 32 + asb * 8]) = lw;
        }
        __syncthreads();  // compiler drains vmcnt+lgkmcnt before barrier

        bf16x8 ah[4], al[4];
        #pragma unroll
        for (int m = 0; m < 4; ++m) {
            ah[m] = *reinterpret_cast<const bf16x8*>(&Ahi[a_rd[m]]);
            al[m] = *reinterpret_cast<const bf16x8*>(&Alo[a_rd[m]]);
        }
        #pragma unroll
        for (int n = 0; n < 4; ++n) {
            const bf16x8 bh = *reinterpret_cast<const bf16x8*>(&Bhi[b_rd[n]]);
            const bf16x8 bl = *reinterpret_cast<const bf16x8*>(&Blo[b_rd[n]]);
            #pragma unroll
            for (int m = 0; m < 4; ++m)
                acc[m][n] = __builtin_amdgcn_mfma_f32_16x16x32_bf16(ah[m], bh, acc[m][n], 0, 0, 0);
            #pragma unroll
            for (int m = 0; m < 4; ++m)
                acc[m][n] = __builtin_amdgcn_mfma_f32_16x16x32_bf16(al[m], bh, acc[m][n], 0, 0, 0);
            #pragma unroll
            for (int m = 0; m < 4; ++m)
                acc[m][n] = __builtin_amdgcn_mfma_f32_16x16x32_bf16(ah[m], bl, acc[m][n], 0, 0, 0);
        }
    }

    __syncthreads();  // all waves done reading A/B before cand overlays Ahi

    // ---- epilogue: + pos_bias, per-row top2 over this wave's 64 cols.
    // C/D layout (m89-verified): col = lane&15, row = (lane>>4)*4 + reg_idx.
    #pragma unroll
    for (int m = 0; m < 4; ++m) {
        #pragma unroll
        for (int j = 0; j < 4; ++j) {
            float v1 = -3.0e38f, v2 = -3.0e38f;
            int s1 = 0;
            #pragma unroll
            for (int n = 0; n < 4; ++n) {  // s ascending in n -> first-max kept
                const float v = acc[m][n][j] + pbv[n];
                if (v > v1) { v2 = v1; v1 = v; s1 = scol[n]; }
                else if (v > v2) { v2 = v; }
            }
            #pragma unroll
            for (int off = 1; off < 16; off <<= 1) {  // 16 column lanes
                const float ov1 = __shfl_xor(v1, off);
                const float ov2 = __shfl_xor(v2, off);
                const int   os1 = __shfl_xor(s1, off);
                if (ov1 > v1 || (ov1 == v1 && os1 < s1)) {
                    v2 = fmaxf(v1, ov2);
                    v1 = ov1; s1 = os1;
                } else {
                    v2 = fmaxf(v2, ov1);
                }
            }
            if (l15 == 0) {
                const int row = m * 16 + l4 * 4 + j;
                cand[wc][row][0] = v1;
                cand[wc][row][1] = __int_as_float(s1);
                cand[wc][row][2] = v2;
            }
        }
    }
    __syncthreads();
    if (tid < 64) {
        const int row = tid;
        float v1 = cand[0][row][0];
        int   s1 = __float_as_int(cand[0][row][1]);
        float v2 = cand[0][row][2];
        #pragma unroll
        for (int g = 1; g < 4; ++g) {   // ascending col-group -> ascending s
            const float a1  = cand[g][row][0];
            const int   as1 = __float_as_int(cand[g][row][1]);
            const float a2  = cand[g][row][2];
            if (a1 > v1) { v2 = fmaxf(v1, a2); v1 = a1; s1 = as1; }
            else         { v2 = fmaxf(v2, a1); }
        }
        const int item = (t0 + row) * N_DIM + i;
        best[item] = s1;
        if (v1 - v2 <= EPS_GAP) {  // ambiguous under split error -> exact pass
            const int idx = atomicAdd(counter, 1);
            if (idx < WCAP) worklist[idx] = item;
        }
    }
}

// ---------------------------------------------------------------------------
// exact fp32 re-resolution of flagged (t,i) items (~700 expected).
// Round-6 rewrite: mem is staged through a padded LDS tile with coalesced
// float4 loads (the old per-thread-row walk touched 64 cache lines per load
// instruction -> ~27 us/item, ~175 us hidden total). The FP summation order
// (kb-blocked, k-ascending, 32-chunk partials) is BIT-IDENTICAL to the
// twice-validated version; only the data movement changed.
__global__ __launch_bounds__(NT)
void exact_fix_kernel(const float* __restrict__ x,
                      const float* __restrict__ mem,
                      const float* __restrict__ pb,
                      const int* __restrict__ counter,
                      const int* __restrict__ worklist,
                      int* __restrict__ best)
{
    __shared__ float xl[D_DIM];          // 4 KB
    __shared__ float Ms[S_DIM][33];      // 33.8 KB; stride 33 -> 2-way banks (free)
    __shared__ float sv[NT];
    __shared__ int   si[NT];
    int cnt = *counter;
    if (cnt > WCAP) cnt = WCAP;
    for (int w = blockIdx.x; w < cnt; w += gridDim.x) {
        const int item = worklist[w];
        const int t  = item / N_DIM;
        const int ii = item - t * N_DIM;
        __syncthreads();  // previous item fully consumed
        #pragma unroll
        for (int p = 0; p < D_DIM / NT; ++p)
            xl[threadIdx.x + p * NT] = x[(size_t)t * D_DIM + threadIdx.x + p * NT];
        const int s = threadIdx.x;
        float acc = 0.f;
        for (int kb = 0; kb < D_DIM; kb += 32) {
            __syncthreads();  // xl ready (first iter) / previous tile consumed
            // stage M[0..255][kb..kb+31]: coalesced float4 global reads
            #pragma unroll
            for (int q = 0; q < 8; ++q) {
                const int f  = threadIdx.x + q * NT;   // 0..2047
                const int sr = f >> 3;                 // row 0..255
                const int c4 = f & 7;                  // float4 col 0..7
                const float4 v = ld4(mem + ((size_t)sr * N_DIM + ii) * D_DIM + kb + c4 * 4);
                Ms[sr][c4 * 4 + 0] = v.x;
                Ms[sr][c4 * 4 + 1] = v.y;
                Ms[sr][c4 * 4 + 2] = v.z;
                Ms[sr][c4 * 4 + 3] = v.w;
            }
            __syncthreads();
            float part = 0.f;   // same 32-chunk partial as the proven kernel
            #pragma unroll
            for (int k = 0; k < 32; ++k) part += xl[kb + k] * Ms[s][k];
            acc += part;
        }
        sv[s] = acc + pb[s * N_DIM + ii];
        si[s] = s;
        __syncthreads();
        for (int off = NT / 2; off >= 1; off >>= 1) {  // first-max semantics
            if (threadIdx.x < off) {
                const float b2 = sv[threadIdx.x + off];
                const int  bi2 = si[threadIdx.x + off];
                if (b2 > sv[threadIdx.x] ||
                    (b2 == sv[threadIdx.x] && bi2 < si[threadIdx.x])) {
                    sv[threadIdx.x] = b2; si[threadIdx.x] = bi2;
                }
            }
            __syncthreads();
        }
        if (threadIdx.x == 0) best[item] = si[0];
    }
}

// ---------------------------------------------------------------------------
// out[b,l,:] = sum_i mem[best_i, i, :]  — 4 rows per block (8192 blocks).
__global__ __launch_bounds__(NT)
void gather_sum_kernel(const float* __restrict__ mem,
                       const float* __restrict__ pb,
                       const int* __restrict__ best,
                       float* __restrict__ out)
{
    const int bl0 = blockIdx.x * GROWS;
    __shared__ int sbi[GROWS][N_DIM];
    if (threadIdx.x < GROWS * N_DIM) {
        const int r = threadIdx.x / N_DIM;
        const int i = threadIdx.x - r * N_DIM;
        const int bl = bl0 + r;
        const int l = bl & (L_DIM - 1);
        const int t = l + i - (N_DIM - 1);
        int bi;
        if (t >= 0) {
            bi = best[(bl + i - (N_DIM - 1)) * N_DIM + i];
        } else {
            float bv = pb[i];  // zero ngram row: argmax over pos_bias (l < 2)
            bi = 0;
            for (int s = 1; s < S_DIM; ++s) {
                const float v = pb[s * N_DIM + i];
                if (v > bv) { bv = v; bi = s; }
            }
        }
        sbi[r][i] = bi;
    }
    __syncthreads();
    const int d = threadIdx.x;
    #pragma unroll
    for (int r = 0; r < GROWS; ++r) {
        const float4 v0 = ld4(mem + (sbi[r][0] * N_DIM + 0) * D_DIM + d * 4);
        const float4 v1 = ld4(mem + (sbi[r][1] * N_DIM + 1) * D_DIM + d * 4);
        const float4 v2 = ld4(mem + (sbi[r][2] * N_DIM + 2) * D_DIM + d * 4);
        float4 o;
        o.x = (v0.x + v1.x) + v2.x;
        o.y = (v0.y + v1.y) + v2.y;
        o.z = (v0.z + v1.z) + v2.z;
        o.w = (v0.w + v1.w) + v2.w;
        *reinterpret_cast<float4*>(out + (size_t)(bl0 + r) * D_DIM + d * 4) = o;
    }
}

// ---------------------------------------------------------------------------
extern "C" void kernel_launch(void* const* d_in, const int* in_sizes, int n_in,
                              void* d_out, int out_size, void* d_ws, size_t ws_size,
                              hipStream_t stream)
{
    const float* x   = (const float*)d_in[0];   // (B, L, D) fp32
    const float* mem = (const float*)d_in[1];   // (S, N, D) fp32
    const float* pb  = (const float*)d_in[2];   // (S, N) fp32
    float* out = (float*)d_out;
    int* best = (int*)d_ws;  // 384 KB — exactly what the proven baseline used

    const int n_rows = B_DIM * L_DIM;           // 32768

    // scratch inside d_out (128 MiB by problem shape; every byte dead before
    // gather_sum rewrites it):  [0,3MiB): mhi,mlo   [4MiB): counter, worklist
    char* ob = (char*)d_out;
    unsigned short* mhi = (unsigned short*)ob;
    unsigned short* mlo = mhi + (size_t)S_DIM * N_DIM * D_DIM;
    int* counter  = (int*)(ob + ((size_t)4 << 20));
    int* worklist = (int*)(ob + ((size_t)4 << 20) + 256);

    split_bf16_kernel<<<192, NT, 0, stream>>>(mem, mhi, mlo, counter,
                                              S_DIM * N_DIM * D_DIM / 4);
    score_mfma_kernel<<<dim3(n_rows / 64, N_DIM), NT, 0, stream>>>(
        x, mhi, mlo, pb, best, counter, worklist);
    exact_fix_kernel<<<512, NT, 0, stream>>>(x, mem, pb, counter, worklist, best);
    gather_sum_kernel<<<n_rows / GROWS, NT, 0, stream>>>(mem, pb, best, out);
}